// Round 7
// baseline (239.029 us; speedup 1.0000x reference)
//
#include <hip/hip_runtime.h>
#include <math.h>

#define HIDDEN   2048
#define NEXPERT  64
#define TOPK     8
#define NTOK     16384
#define TOKB     16          // tokens per block = one 16-row M tile
#define RSQRT_H  0.02209708691207961
#define WSCALE   64.0        // f16 weight-split scale; undone in epilogue

typedef __attribute__((ext_vector_type(8))) _Float16 v8h;
typedef __attribute__((ext_vector_type(4))) float    v4f;

// Weight prep into B-fragment order (identical to R6, numerics verified):
// wf[ks(64)][nt(4)][hl(2)][lane(64)][j(8)] f16;  B[k][n]: n=nt*16+(lane&15),
// k=ks*32+(lane>>4)*8+j;  v = w*scale*64, Dekker split hi/lo.
__global__ __launch_bounds__(256) void prep_wf(
    const float* __restrict__ w, const float* __restrict__ scale,
    unsigned short* __restrict__ wf)
{
    int i    = blockIdx.x * 256 + threadIdx.x;   // 131072
    int j    = i & 7;
    int lane = (i >> 3) & 63;
    int nt   = (i >> 9) & 3;
    int ks   = i >> 11;
    int e    = nt * 16 + (lane & 15);
    int k    = ks * 32 + (lane >> 4) * 8 + j;
    float v  = w[e * HIDDEN + k] * scale[k] * (float)WSCALE;
    _Float16 vh = (_Float16)v;
    _Float16 vl = (_Float16)(v - (float)vh);
    size_t base = (((size_t)(ks * 4 + nt) * 2) * 64 + lane) * 8 + j;
    wf[base]       = __builtin_bit_cast(unsigned short, vh);
    wf[base + 512] = __builtin_bit_cast(unsigned short, vl);
}

// 16 tokens/block, 4 waves splitting k contiguously (512 k each).
// NO LDS staging, NO barriers in the K-loop: each lane loads its A-fragment
// rows directly from global (16 full cache lines per kstep), converts
// in-register (Dekker f16 split), MFMAs against L2-resident weight frags.
__global__ __launch_bounds__(256, 4) void router_main(
    const float* __restrict__ h, const unsigned short* __restrict__ wf,
    const float* __restrict__ pes,
    float* __restrict__ out_w, float* __restrict__ out_i, float* __restrict__ out_c)
{
    __shared__ float  part[4 * 1056];   // [wave][tok(16)][66] partial logits (2-way max)
    __shared__ float  lg[16 * 68];      // combined logits [tok][68] (f4-aligned rows)
    __shared__ float  ssp[256];         // [wave][quad][m] sum-of-squares partials
    __shared__ double rd[16];           // per-token rms*const factor (f64)
    __shared__ int    hist[NEXPERT];

    const int tid  = (int)threadIdx.x;
    const int w    = __builtin_amdgcn_readfirstlane(tid >> 6);   // wave = k-quarter
    const int lane = tid & 63;
    const int m    = lane & 15;          // token within tile (A row / D row)
    const int quad = lane >> 4;
    const int t0   = (int)blockIdx.x * TOKB;

    if (tid < NEXPERT) hist[tid] = 0;

    // A-fragment source: row = token t0+m, k window = w*512 + s*32 + quad*8
    const float* __restrict__ hrow = h + (size_t)(t0 + m) * HIDDEN + w * 512 + quad * 8;
    const unsigned short* __restrict__ wb = wf + (size_t)w * 65536 + lane * 8;

    v4f acc[4];
#pragma unroll
    for (int nt = 0; nt < 4; ++nt) acc[nt] = (v4f)0.f;
    float ss = 0.f;

#pragma unroll 4
    for (int s = 0; s < 16; ++s) {
        float4 va = *(const float4*)(hrow + s * 32);
        float4 vb = *(const float4*)(hrow + s * 32 + 4);
        ss = fmaf(va.x, va.x, fmaf(va.y, va.y, fmaf(va.z, va.z, fmaf(va.w, va.w, ss))));
        ss = fmaf(vb.x, vb.x, fmaf(vb.y, vb.y, fmaf(vb.z, vb.z, fmaf(vb.w, vb.w, ss))));
        v8h ah, al;
        ah[0] = (_Float16)va.x;  al[0] = (_Float16)(va.x - (float)ah[0]);
        ah[1] = (_Float16)va.y;  al[1] = (_Float16)(va.y - (float)ah[1]);
        ah[2] = (_Float16)va.z;  al[2] = (_Float16)(va.z - (float)ah[2]);
        ah[3] = (_Float16)va.w;  al[3] = (_Float16)(va.w - (float)ah[3]);
        ah[4] = (_Float16)vb.x;  al[4] = (_Float16)(vb.x - (float)ah[4]);
        ah[5] = (_Float16)vb.y;  al[5] = (_Float16)(vb.y - (float)ah[5]);
        ah[6] = (_Float16)vb.z;  al[6] = (_Float16)(vb.z - (float)ah[6]);
        ah[7] = (_Float16)vb.w;  al[7] = (_Float16)(vb.w - (float)ah[7]);
#pragma unroll
        for (int nt = 0; nt < 4; ++nt) {
            const unsigned short* bp = wb + s * 4096 + nt * 1024;
            v8h bh = *(const v8h*)bp;
            v8h bl = *(const v8h*)(bp + 512);
            acc[nt] = __builtin_amdgcn_mfma_f32_16x16x32_f16(ah, bh, acc[nt], 0, 0, 0);
            acc[nt] = __builtin_amdgcn_mfma_f32_16x16x32_f16(ah, bl, acc[nt], 0, 0, 0);
            acc[nt] = __builtin_amdgcn_mfma_f32_16x16x32_f16(al, bh, acc[nt], 0, 0, 0);
        }
    }

    // D layout (m89-verified): row token = quad*4+reg, col expert = nt*16+m
#pragma unroll
    for (int nt = 0; nt < 4; ++nt)
#pragma unroll
        for (int r = 0; r < 4; ++r)
            part[w * 1056 + (quad * 4 + r) * 66 + nt * 16 + m] = acc[nt][r];
    ssp[w * 64 + quad * 16 + m] = ss;
    __syncthreads();                               // B1: partials visible

    if (tid < TOKB) {                              // per-token rms factor (f64)
        double s = 0.0;
#pragma unroll
        for (int p = 0; p < 16; ++p) s += (double)ssp[(p >> 2) * 64 + (p & 3) * 16 + tid];
        rd[tid] = (1.0 / sqrt(s * (1.0 / (double)HIDDEN) + 1e-6)) * (RSQRT_H / WSCALE);
    }
    // combine the 4 k-quarter partials (independent of rd)
    float cs[4];
#pragma unroll
    for (int i = 0; i < 4; ++i) {
        int t = i * 4 + w;
        cs[i] = (part[t * 66 + lane]        + part[1056 + t * 66 + lane])
              + (part[2112 + t * 66 + lane] + part[3168 + t * 66 + lane]);
    }
    __syncthreads();                               // B2: rd ready
#pragma unroll
    for (int i = 0; i < 4; ++i) {
        int t = i * 4 + w;
        lg[t * 68 + lane] = (float)((double)cs[i] * rd[t]);
    }
    __syncthreads();                               // B3: logits visible

    // ---- rank-count top-8: lane = expert; stream 64 logits via LDS broadcast.
    // rank = #{j: v_j>v || (v_j==v && j<lane)}  -> ties to lowest index (jax);
    // rank<8 selects, rank is the output slot, running max = softmax m0.
    const float mypes = pes[lane];
    for (int i = 0; i < 4; ++i) {
        const int tok = w * 4 + i;
        const float myv = lg[tok * 68 + lane];
        int rank = 0;
        float mx = -3.402823466e38f;
#pragma unroll
        for (int j4 = 0; j4 < 64; j4 += 4) {
            float4 q = *(const float4*)(&lg[tok * 68 + j4]);
            mx = fmaxf(mx, fmaxf(fmaxf(q.x, q.y), fmaxf(q.z, q.w)));
            rank += (q.x > myv || (q.x == myv && (j4 + 0) < lane)) ? 1 : 0;
            rank += (q.y > myv || (q.y == myv && (j4 + 1) < lane)) ? 1 : 0;
            rank += (q.z > myv || (q.z == myv && (j4 + 2) < lane)) ? 1 : 0;
            rank += (q.w > myv || (q.w == myv && (j4 + 3) < lane)) ? 1 : 0;
        }
        float ev = (rank < TOPK) ? expf(myv - mx) : 0.f;
        float es = ev;
        es += __shfl_xor(es, 1, 64);
        es += __shfl_xor(es, 2, 64);
        es += __shfl_xor(es, 4, 64);
        es += __shfl_xor(es, 8, 64);
        es += __shfl_xor(es, 16, 64);
        es += __shfl_xor(es, 32, 64);
        if (rank < TOPK) {
            size_t o = (size_t)(t0 + tok) * TOPK + rank;
            out_w[o] = (ev / es) * mypes;
            out_i[o] = (float)lane;                // d_out read as float32
            atomicAdd(&hist[lane], 1);
        }
    }

    __syncthreads();                               // B4: hist complete
    if (tid < NEXPERT)
        atomicAdd(&out_c[tid], (float)hist[tid]);
}

extern "C" void kernel_launch(void* const* d_in, const int* in_sizes, int n_in,
                              void* d_out, int out_size, void* d_ws, size_t ws_size,
                              hipStream_t stream) {
    const float* h     = (const float*)d_in[0];   // [4,4096,2048] f32
    const float* scale = (const float*)d_in[1];   // [2048] f32
    const float* w     = (const float*)d_in[2];   // [64,2048] f32
    const float* pes   = (const float*)d_in[3];   // [64] f32

    unsigned short* wf = (unsigned short*)d_ws;   // 512 KB f16 fragment bank

    float* out_w = (float*)d_out;                                  // [16384,8]
    float* out_i = (float*)d_out + (size_t)NTOK * TOPK;            // [16384,8] idx-as-f32
    float* out_c = (float*)d_out + (size_t)NTOK * TOPK * 2;        // [64]

    hipMemsetAsync(out_c, 0, NEXPERT * sizeof(float), stream);

    prep_wf<<<512, 256, 0, stream>>>(w, scale, wf);

    // 1024 blocks (4/CU, 16 waves/CU) x 256 thr; barrier-free K-loop
    router_main<<<NTOK / TOKB, 256, 0, stream>>>(h, wf, pes, out_w, out_i, out_c);
}